// Round 12
// baseline (213.424 us; speedup 1.0000x reference)
//
#include <hip/hip_runtime.h>
#include <hip/hip_bf16.h>
#include <stdint.h>

#define NSEQ   2048
#define DMODEL 1024
#define NH     16
#define DH     64
#define BATCH  2
#define BH     (BATCH*NH)           // 32
#define MROWS  (BATCH*NSEQ)         // 4096

typedef unsigned short u16;
typedef __attribute__((ext_vector_type(8))) short s16x8;
typedef __attribute__((ext_vector_type(4))) float f32x4;

__device__ __forceinline__ void load16_to_lds(const void* g, void* l) {
    __builtin_amdgcn_global_load_lds(
        (const __attribute__((address_space(1))) void*)g,
        (__attribute__((address_space(3))) void*)l,
        16, 0, 0);
}

__device__ __forceinline__ float bf2f(u16 u) {
    union { uint32_t i; float f; } x; x.i = ((uint32_t)u) << 16; return x.f;
}
__device__ __forceinline__ u16 f2bf(float f) {
    union { float f; uint32_t i; } x; x.f = f;
    uint32_t r = x.i + 0x7FFFu + ((x.i >> 16) & 1u);  // RNE
    return (u16)(r >> 16);
}
// pack two fp32 -> bf16 pair (lo in low16, hi in high16)
__device__ __forceinline__ uint32_t pk2(float lo, float hi) {
    union { float f; uint32_t i; } a, b; a.f = lo; b.f = hi;
    return __builtin_amdgcn_perm(b.i + 0x7FFFu, a.i + 0x7FFFu, 0x07060302u);
}

// ---------------------------------------------------------------------------
// fp32 -> bf16 conversion. grid (512,1,8): z<4 -> quarter-slices of x (4M),
// z=4..7 -> wq/wk/wv/wo (1M each).
// ---------------------------------------------------------------------------
__global__ void cvt_kernel(
    const float* __restrict__ x,
    const float* __restrict__ wq, const float* __restrict__ wk,
    const float* __restrict__ wv, const float* __restrict__ wo,
    u16* __restrict__ xb,
    u16* __restrict__ wqb, u16* __restrict__ wkb,
    u16* __restrict__ wvb, u16* __restrict__ wob)
{
    int z = blockIdx.z;
    const float* s = (z < 4) ? x  : (z == 4 ? wq  : z == 5 ? wk  : z == 6 ? wv  : wo);
    u16*         d = (z < 4) ? xb : (z == 4 ? wqb : z == 5 ? wkb : z == 6 ? wvb : wob);
    size_t off = (z < 4) ? ((size_t)z << 20) : 0;
    size_t i = off + (size_t)blockIdx.x * 2048 + (size_t)threadIdx.x * 8;
    float4 a = *(const float4*)(s + i);
    float4 b = *(const float4*)(s + i + 4);
    s16x8 v;
    v[0] = (short)f2bf(a.x); v[1] = (short)f2bf(a.y);
    v[2] = (short)f2bf(a.z); v[3] = (short)f2bf(a.w);
    v[4] = (short)f2bf(b.x); v[5] = (short)f2bf(b.y);
    v[6] = (short)f2bf(b.z); v[7] = (short)f2bf(b.w);
    *(s16x8*)(d + i) = v;
}

// ---------------------------------------------------------------------------
// QKV GEMM: C = A @ W^T. 64(M)x128(N) tiles, BK=64, 256 threads, 3 blocks/CU.
// grid (8,64,3) = 1536 blocks -> exactly 2 full rounds at 3/CU (no tail;
// the old 128x128 grid was 768 blocks = 1.5 rounds at 2/CU).
// acc 2x4 (32 AGPR) keeps total regs ~132 <= the 170 budget of bound 3.
// XOR chunk swizzle: chunk c of row r stored at c ^ (r&7).
// z<2 : bf16 scatter -> [B,H,N,DH] (Q,K) + fused hyperbolic tables
// z==2: bf16 transposed scatter -> [B,H,DH,N]  (V -> Vt, fused)
// ---------------------------------------------------------------------------
__global__ __launch_bounds__(256, 3) void gemm_bt(
    const u16* __restrict__ A,
    const u16* __restrict__ W0, const u16* __restrict__ W1, const u16* __restrict__ W2,
    void* __restrict__ C0, void* __restrict__ C1, void* __restrict__ C2,
    float2* __restrict__ qtab, float2* __restrict__ ktab)
{
    __shared__ __align__(16) char smem[24576];
    char* ldsA = smem;            // 8KB: 64 rows x 8 chunks x 16B
    char* ldsW = smem + 8192;     // 16KB: 128 rows x 8 chunks

    const u16* W = (blockIdx.z == 0) ? W0 : (blockIdx.z == 1 ? W1 : W2);
    void*      C = (blockIdx.z == 0) ? C0 : (blockIdx.z == 1 ? C1 : C2);

    const int tid  = threadIdx.x;
    const int lane = tid & 63;
    const int w    = tid >> 6;
    const int quad = lane >> 4;
    const int l15  = lane & 15;
    const int m0   = blockIdx.y * 64;
    const int n0   = blockIdx.x * 128;
    const int wr   = (w >> 1) * 32;
    const int wc   = (w & 1) * 64;

    f32x4 acc[2][4];
    const f32x4 fz = {0.f, 0.f, 0.f, 0.f};
    #pragma unroll
    for (int i = 0; i < 2; i++)
        #pragma unroll
        for (int j = 0; j < 4; j++) acc[i][j] = fz;

    for (int k0 = 0; k0 < DMODEL; k0 += 64) {
        __syncthreads();
        #pragma unroll
        for (int i = 0; i < 2; i++) {           // A: 512 chunks
            int linear = tid + i * 256;
            int row = linear >> 3, sc = linear & 7, gc = sc ^ (row & 7);
            load16_to_lds(A + (size_t)(m0 + row) * DMODEL + k0 + gc * 8,
                          ldsA + linear * 16);
        }
        #pragma unroll
        for (int i = 0; i < 4; i++) {           // W: 1024 chunks
            int linear = tid + i * 256;
            int row = linear >> 3, sc = linear & 7, gc = sc ^ (row & 7);
            load16_to_lds(W + (size_t)(n0 + row) * DMODEL + k0 + gc * 8,
                          ldsW + linear * 16);
        }
        __syncthreads();
        #pragma unroll
        for (int ks = 0; ks < 2; ks++) {
            s16x8 af[2], bf[4];
            #pragma unroll
            for (int mi = 0; mi < 2; mi++) {
                int row = wr + mi * 16 + l15;
                int ch  = (ks * 4 + quad) ^ (row & 7);
                af[mi] = *(const s16x8*)(ldsA + row * 128 + ch * 16);
            }
            #pragma unroll
            for (int ni = 0; ni < 4; ni++) {
                int row = wc + ni * 16 + l15;
                int ch  = (ks * 4 + quad) ^ (row & 7);
                bf[ni] = *(const s16x8*)(ldsW + row * 128 + ch * 16);
            }
            #pragma unroll
            for (int mi = 0; mi < 2; mi++)
                #pragma unroll
                for (int ni = 0; ni < 4; ni++)
                    acc[mi][ni] = __builtin_amdgcn_mfma_f32_16x16x32_bf16(
                        af[mi], bf[ni], acc[mi][ni], 0, 0, 0);
        }
    }

    if (blockIdx.z < 2) {
        // Q / K: scatter + fused factor tables.
        float2* tab = (blockIdx.z == 0) ? qtab : ktab;
        int h = (n0 + wc) >> 6;      // wave's 64-col span = one head
        #pragma unroll
        for (int mi = 0; mi < 2; mi++)
            #pragma unroll
            for (int r = 0; r < 4; r++) {
                int m = m0 + wr + mi * 16 + quad * 4 + r;
                int b = m >> 11, n = m & (NSEQ - 1);
                float ss = 0.f;
                #pragma unroll
                for (int ni = 0; ni < 4; ni++) {
                    int o = n0 + wc + ni * 16 + l15;
                    int d = o & 63;
                    float v = acc[mi][ni][r];
                    ss = fmaf(v, v, ss);
                    ((u16*)C)[(((size_t)(b * NH + h)) * NSEQ + n) * DH + d] = f2bf(v);
                }
                // butterfly over the 16-lane group
                ss += __shfl_xor(ss, 1);
                ss += __shfl_xor(ss, 2);
                ss += __shfl_xor(ss, 4);
                ss += __shfl_xor(ss, 8);
                if (l15 == 0) {
                    float rr = 1.0f / (1.0f - ss);
                    tab[(size_t)(b * NH + h) * NSEQ + n] =
                        make_float2((1.0f + ss) * rr, 2.0f * rr);
                }
            }
    } else {
        // V transposed: r=0..3 are consecutive n -> packed 8B stores
        #pragma unroll
        for (int mi = 0; mi < 2; mi++) {
            int mrow = m0 + wr + mi * 16 + quad * 4;
            int b = mrow >> 11, n = mrow & (NSEQ - 1);
            #pragma unroll
            for (int ni = 0; ni < 4; ni++) {
                int o = n0 + wc + ni * 16 + l15;
                int h = o >> 6, d = o & 63;
                uint2 st;
                st.x = pk2(acc[mi][ni][0], acc[mi][ni][1]);
                st.y = pk2(acc[mi][ni][2], acc[mi][ni][3]);
                *(uint2*)((u16*)C + (((size_t)(b * NH + h)) * DH + d) * NSEQ + n) = st;
            }
        }
    }
}

// ---------------------------------------------------------------------------
// Output-projection GEMM: C(fp32) = A @ W^T, 64(M)x128(N) tiles, 512 blocks.
// ---------------------------------------------------------------------------
__global__ __launch_bounds__(256, 3) void gemm_m64(
    const u16* __restrict__ A, const u16* __restrict__ W, float* __restrict__ C)
{
    __shared__ __align__(16) char smem[24576];
    char* ldsA = smem;            // 8KB: 64 rows x 8 chunks x 16B
    char* ldsW = smem + 8192;     // 16KB: 128 rows x 8 chunks

    const int tid  = threadIdx.x;
    const int lane = tid & 63;
    const int w    = tid >> 6;
    const int quad = lane >> 4;
    const int l15  = lane & 15;
    const int m0   = blockIdx.y * 64;
    const int n0   = blockIdx.x * 128;
    const int wr   = (w >> 1) * 32;
    const int wc   = (w & 1) * 64;

    f32x4 acc[2][4];
    const f32x4 fz = {0.f, 0.f, 0.f, 0.f};
    #pragma unroll
    for (int i = 0; i < 2; i++)
        #pragma unroll
        for (int j = 0; j < 4; j++) acc[i][j] = fz;

    for (int k0 = 0; k0 < DMODEL; k0 += 64) {
        __syncthreads();
        #pragma unroll
        for (int i = 0; i < 2; i++) {           // A: 512 chunks
            int linear = tid + i * 256;
            int row = linear >> 3, sc = linear & 7, gc = sc ^ (row & 7);
            load16_to_lds(A + (size_t)(m0 + row) * DMODEL + k0 + gc * 8,
                          ldsA + linear * 16);
        }
        #pragma unroll
        for (int i = 0; i < 4; i++) {           // W: 1024 chunks
            int linear = tid + i * 256;
            int row = linear >> 3, sc = linear & 7, gc = sc ^ (row & 7);
            load16_to_lds(W + (size_t)(n0 + row) * DMODEL + k0 + gc * 8,
                          ldsW + linear * 16);
        }
        __syncthreads();
        #pragma unroll
        for (int ks = 0; ks < 2; ks++) {
            s16x8 af[2], bf[4];
            #pragma unroll
            for (int mi = 0; mi < 2; mi++) {
                int row = wr + mi * 16 + l15;
                int ch  = (ks * 4 + quad) ^ (row & 7);
                af[mi] = *(const s16x8*)(ldsA + row * 128 + ch * 16);
            }
            #pragma unroll
            for (int ni = 0; ni < 4; ni++) {
                int row = wc + ni * 16 + l15;
                int ch  = (ks * 4 + quad) ^ (row & 7);
                bf[ni] = *(const s16x8*)(ldsW + row * 128 + ch * 16);
            }
            #pragma unroll
            for (int mi = 0; mi < 2; mi++)
                #pragma unroll
                for (int ni = 0; ni < 4; ni++)
                    acc[mi][ni] = __builtin_amdgcn_mfma_f32_16x16x32_bf16(
                        af[mi], bf[ni], acc[mi][ni], 0, 0, 0);
        }
    }

    #pragma unroll
    for (int mi = 0; mi < 2; mi++)
        #pragma unroll
        for (int r = 0; r < 4; r++) {
            int m = m0 + wr + mi * 16 + quad * 4 + r;
            #pragma unroll
            for (int ni = 0; ni < 4; ni++) {
                int o = n0 + wc + ni * 16 + l15;
                C[(size_t)m * DMODEL + o] = acc[mi][ni][r];
            }
        }
}

// ---------------------------------------------------------------------------
// Attention, transposed-score form, 32 q per wave, IN-BLOCK kv-split.
// grid (NSEQ/128, BH), 512 threads (8 waves): waves 0-3 = j in [0,1024),
// waves 4-7 = j in [1024,2048), same 128-q tile.  Each group stages its own
// K/Vt tiles in its 32KB half of LDS.  Epilogue: group 1 drops fp32
// oacc/lsum into LDS (stride-68 pad), group 0 adds, normalizes, writes Attw.
// Scalar transform (pk-f32 variants spill -- do not revisit).
// PLATEAU: occupancy reg-capped (16 waves x ~104 = 1664/2048); LDS 64KB.
// ---------------------------------------------------------------------------
__global__ __launch_bounds__(512, 4) void attn_kernel(
    const u16* __restrict__ Q,      // [BH][NSEQ][DH]
    const u16* __restrict__ K,      // [BH][NSEQ][DH]
    const u16* __restrict__ Vt,     // [BH][DH][NSEQ]
    const float2* __restrict__ qtab,
    const float2* __restrict__ ktab,
    u16* __restrict__ Attw)         // [B][NSEQ][DMODEL] bf16
{
    __shared__ __align__(16) char smem[65536];

    const int tid  = threadIdx.x;
    const int lane = tid & 63;
    const int w    = tid >> 6;       // 0..7
    const int g    = w >> 2;         // j-half group
    const int wq_  = w & 3;
    const int quad = lane >> 4;
    const int l15  = lane & 15;
    const int bh   = blockIdx.y;
    const int i0   = blockIdx.x * 128;
    const int qbase = i0 + wq_ * 32;
    const int gt   = tid & 255;      // tid within group

    char* ldsK = smem + g * 16384;
    char* ldsV = smem + 32768 + g * 16384;

    // Q fragments (B-operand layout), pre-scaled by Rr
    s16x8 qf[2][2];                 // [qt][ks]
    float Pr[2];
    #pragma unroll
    for (int qt = 0; qt < 2; qt++) {
        int qrow = qbase + qt * 16 + l15;
        float2 qt2 = qtab[(size_t)bh * NSEQ + qrow];
        Pr[qt] = qt2.x;
        float Rr = qt2.y;
        #pragma unroll
        for (int ks = 0; ks < 2; ks++) {
            s16x8 raw = *(const s16x8*)(Q + ((size_t)bh * NSEQ + qrow) * DH
                                        + ks * 32 + quad * 8);
            s16x8 sc;
            #pragma unroll
            for (int e = 0; e < 8; e++)
                sc[e] = (short)f2bf(bf2f((u16)raw[e]) * Rr);
            qf[qt][ks] = sc;
        }
    }

    // bpermute source-lane byte indices
    const int idx0 = ((quad & 1) * 32 + l15) * 4;
    const int idx2 = idx0 + 64;
    const bool selhi = quad >= 2;

    const f32x4 fz = {0.f, 0.f, 0.f, 0.f};
    f32x4 oacc[2][4];               // [qt][d-tile], O^T C-layout (col=q, row=d)
    f32x4 lsum[2];
    #pragma unroll
    for (int qt = 0; qt < 2; qt++) {
        lsum[qt] = fz;
        #pragma unroll
        for (int ni = 0; ni < 4; ni++) oacc[qt][ni] = fz;
    }

    s16x8 ones;
    #pragma unroll
    for (int j = 0; j < 8; j++) ones[j] = (short)0x3F80;  // bf16 1.0

    const float2* ktb = ktab + (size_t)bh * NSEQ;

    for (int jj = 0; jj < NSEQ / 2; jj += 128) {
        int j0 = g * (NSEQ / 2) + jj;
        __syncthreads();
        #pragma unroll
        for (int i = 0; i < 4; i++) {
            int linear = gt + i * 256;    // 0..1023 within group
            {   // K tile: 128 rows x 8 chunks, swz8
                int row = linear >> 3, sc = linear & 7, gc = sc ^ (row & 7);
                load16_to_lds(K + ((size_t)bh * NSEQ + j0 + row) * DH + gc * 8,
                              ldsK + linear * 16);
            }
            {   // Vt tile: 64 rows x 16 chunks, swz16
                int d = linear >> 4, sc = linear & 15, gc = sc ^ (d & 15);
                load16_to_lds(Vt + ((size_t)bh * DH + d) * NSEQ + j0 + gc * 8,
                              ldsV + linear * 16);
            }
        }
        __syncthreads();

        #pragma unroll
        for (int cb = 0; cb < 4; cb++) {          // 32 j per chunk
            // S' = K Q'^T: two 16-j tiles x two q-tiles (kf shared across qt)
            f32x4 s2[2][2];                       // [qt][t]
            #pragma unroll
            for (int qt = 0; qt < 2; qt++)
                #pragma unroll
                for (int t = 0; t < 2; t++) s2[qt][t] = fz;
            #pragma unroll
            for (int t = 0; t < 2; t++) {
                int row = (cb * 2 + t) * 16 + l15;
                #pragma unroll
                for (int ks = 0; ks < 2; ks++) {
                    s16x8 kf = *(const s16x8*)(ldsK + row * 128
                                 + (((ks * 4 + quad) ^ (row & 7)) * 16));
                    #pragma unroll
                    for (int qt = 0; qt < 2; qt++)
                        s2[qt][t] = __builtin_amdgcn_mfma_f32_16x16x32_bf16(
                            kf, qf[qt][ks], s2[qt][t], 0, 0, 0);
                }
            }
            // transform + pack: z = Pr*Pc - s2*Rc (scalar form)
            uint32_t d0[2][2], d1[2][2];          // [qt][t]
            #pragma unroll
            for (int t = 0; t < 2; t++) {
                const f32x4* kt = (const f32x4*)(ktb + j0 + (cb * 2 + t) * 16 + quad * 4);
                f32x4 c01 = kt[0], c23 = kt[1];
                #pragma unroll
                for (int qt = 0; qt < 2; qt++) {
                    float z0 = fmaf(-s2[qt][t][0], c01.y, Pr[qt] * c01.x);
                    float z1 = fmaf(-s2[qt][t][1], c01.w, Pr[qt] * c01.z);
                    float z2 = fmaf(-s2[qt][t][2], c23.y, Pr[qt] * c23.x);
                    float z3 = fmaf(-s2[qt][t][3], c23.w, Pr[qt] * c23.z);
                    z0 = fmaxf(z0, 1.0f); z1 = fmaxf(z1, 1.0f);
                    z2 = fmaxf(z2, 1.0f); z3 = fmaxf(z3, 1.0f);
                    float p0 = z0 - __builtin_amdgcn_sqrtf(fmaf(z0, z0, -1.0f));
                    float p1 = z1 - __builtin_amdgcn_sqrtf(fmaf(z1, z1, -1.0f));
                    float p2 = z2 - __builtin_amdgcn_sqrtf(fmaf(z2, z2, -1.0f));
                    float p3 = z3 - __builtin_amdgcn_sqrtf(fmaf(z3, z3, -1.0f));
                    d0[qt][t] = pk2(p0, p1);
                    d1[qt][t] = pk2(p2, p3);
                }
            }
            // build P' B-fragments via cross-lane pulls
            s16x8 pf[2];
            #pragma unroll
            for (int qt = 0; qt < 2; qt++) {
                int a0 = __builtin_amdgcn_ds_bpermute(idx0, (int)d0[qt][0]);
                int b0 = __builtin_amdgcn_ds_bpermute(idx0, (int)d0[qt][1]);
                int a1 = __builtin_amdgcn_ds_bpermute(idx0, (int)d1[qt][0]);
                int b1 = __builtin_amdgcn_ds_bpermute(idx0, (int)d1[qt][1]);
                int a2 = __builtin_amdgcn_ds_bpermute(idx2, (int)d0[qt][0]);
                int b2 = __builtin_amdgcn_ds_bpermute(idx2, (int)d0[qt][1]);
                int a3 = __builtin_amdgcn_ds_bpermute(idx2, (int)d1[qt][0]);
                int b3 = __builtin_amdgcn_ds_bpermute(idx2, (int)d1[qt][1]);
                union { int i[4]; s16x8 v; } pu;
                pu.i[0] = selhi ? b0 : a0;
                pu.i[1] = selhi ? b1 : a1;
                pu.i[2] = selhi ? b2 : a2;
                pu.i[3] = selhi ? b3 : a3;
                pf[qt] = pu.v;
            }

            // O^T += Vt-tile * P' (vf shared across qt) ; lsum += ones * P'
            #pragma unroll
            for (int ni = 0; ni < 4; ni++) {
                int d = ni * 16 + l15;
                s16x8 vf = *(const s16x8*)(ldsV + d * 256
                             + (((cb * 4 + quad) ^ (d & 15)) * 16));
                #pragma unroll
                for (int qt = 0; qt < 2; qt++)
                    oacc[qt][ni] = __builtin_amdgcn_mfma_f32_16x16x32_bf16(
                        vf, pf[qt], oacc[qt][ni], 0, 0, 0);
            }
            #pragma unroll
            for (int qt = 0; qt < 2; qt++)
                lsum[qt] = __builtin_amdgcn_mfma_f32_16x16x32_bf16(
                    ones, pf[qt], lsum[qt], 0, 0, 0);
        }
    }

    // ---- in-block combine: group 1 -> LDS, group 0 adds + stores ----
    __syncthreads();
    float* oxfer = (float*)smem;                 // [128 q][68] fp32 (pad 68)
    float* lxfer = (float*)(smem + 34816);       // [128] fp32
    if (g == 1) {
        #pragma unroll
        for (int qt = 0; qt < 2; qt++) {
            int ql = wq_ * 32 + qt * 16 + l15;
            #pragma unroll
            for (int ni = 0; ni < 4; ni++)
                *(f32x4*)(oxfer + ql * 68 + ni * 16 + quad * 4) = oacc[qt][ni];
            if (quad == 0) lxfer[ql] = lsum[qt][0];
        }
    }
    __syncthreads();
    if (g == 0) {
        const int b = bh >> 4, h = bh & 15;
        #pragma unroll
        for (int qt = 0; qt < 2; qt++) {
            int ql = wq_ * 32 + qt * 16 + l15;
            float rls = 1.0f / (lsum[qt][0] + lxfer[ql]);
            size_t obase = ((size_t)b * NSEQ + qbase + qt * 16 + l15) * DMODEL
                           + h * DH + quad * 4;
            #pragma unroll
            for (int ni = 0; ni < 4; ni++) {
                f32x4 add = *(const f32x4*)(oxfer + ql * 68 + ni * 16 + quad * 4);
                f32x4 o = oacc[qt][ni] + add;
                uint2 st;
                st.x = pk2(o[0] * rls, o[1] * rls);
                st.y = pk2(o[2] * rls, o[3] * rls);
                *(uint2*)(Attw + obase + ni * 16) = st;
            }
        }
    }
}

// ---------------------------------------------------------------------------
extern "C" void kernel_launch(void* const* d_in, const int* in_sizes, int n_in,
                              void* d_out, int out_size, void* d_ws, size_t ws_size,
                              hipStream_t stream)
{
    const float* x  = (const float*)d_in[0];
    const float* wq = (const float*)d_in[1];
    const float* wk = (const float*)d_in[2];
    const float* wv = (const float*)d_in[3];
    const float* wo = (const float*)d_in[4];
    float* out = (float*)d_out;

    const size_t QSZ = (size_t)BH * NSEQ * DH;   // 4,194,304 elements
    const size_t WSZ = (size_t)DMODEL * DMODEL;  // 1,048,576 elements
    u16* xb   = (u16*)d_ws;           // 4M elem; reused as Attw after attn
    u16* wqb  = xb  + QSZ;
    u16* wkb  = wqb + WSZ;
    u16* wvb  = wkb + WSZ;
    u16* wob  = wvb + WSZ;
    u16* Qw   = wob + WSZ;
    u16* Kw   = Qw + QSZ;
    u16* Vtw  = Kw + QSZ;             // V written pre-transposed by gemm
    float2* qtab = (float2*)(Vtw + QSZ);
    float2* ktab = qtab + (size_t)BH * NSEQ;
    u16*    Attw = xb;                // overlay: x bf16 dead after QKV

    // 0. fp32 -> bf16 conversions
    cvt_kernel<<<dim3(512, 1, 8), 256, 0, stream>>>(x, wq, wk, wv, wo,
                                                    xb, wqb, wkb, wvb, wob);
    // 1. Q/K/V projections; V pre-transposed; Q/K factor tables fused
    //    64x128 tiles -> 1536 blocks -> exactly 2 rounds at 3 blocks/CU
    gemm_bt<<<dim3(8, 64, 3), 256, 0, stream>>>(xb, wqb, wkb, wvb, Qw, Kw, Vtw,
                                                qtab, ktab);
    // 2. attention (32 q/wave, in-block kv-split, writes Attw directly)
    attn_kernel<<<dim3(NSEQ / 128, BH), 512, 0, stream>>>(Qw, Kw, Vtw, qtab, ktab,
                                                          Attw);
    // 3. output projection -> d_out (fp32), 64-row tiles
    gemm_m64<<<dim3(8, 64), 256, 0, stream>>>(Attw, wob, out);
}

// Round 13
// 199.622 us; speedup vs baseline: 1.0691x; 1.0691x over previous
//
#include <hip/hip_runtime.h>
#include <hip/hip_bf16.h>
#include <stdint.h>

#define NSEQ   2048
#define DMODEL 1024
#define NH     16
#define DH     64
#define BATCH  2
#define BH     (BATCH*NH)           // 32
#define MROWS  (BATCH*NSEQ)         // 4096

typedef unsigned short u16;
typedef __attribute__((ext_vector_type(8))) short s16x8;
typedef __attribute__((ext_vector_type(4))) float f32x4;

__device__ __forceinline__ void load16_to_lds(const void* g, void* l) {
    __builtin_amdgcn_global_load_lds(
        (const __attribute__((address_space(1))) void*)g,
        (__attribute__((address_space(3))) void*)l,
        16, 0, 0);
}

__device__ __forceinline__ float bf2f(u16 u) {
    union { uint32_t i; float f; } x; x.i = ((uint32_t)u) << 16; return x.f;
}
__device__ __forceinline__ u16 f2bf(float f) {
    union { float f; uint32_t i; } x; x.f = f;
    uint32_t r = x.i + 0x7FFFu + ((x.i >> 16) & 1u);  // RNE
    return (u16)(r >> 16);
}
// pack two fp32 -> bf16 pair (lo in low16, hi in high16)
__device__ __forceinline__ uint32_t pk2(float lo, float hi) {
    union { float f; uint32_t i; } a, b; a.f = lo; b.f = hi;
    return __builtin_amdgcn_perm(b.i + 0x7FFFu, a.i + 0x7FFFu, 0x07060302u);
}

// ---------------------------------------------------------------------------
// fp32 -> bf16 conversion. grid (512,1,8): z<4 -> quarter-slices of x (4M),
// z=4..7 -> wq/wk/wv/wo (1M each).
// ---------------------------------------------------------------------------
__global__ void cvt_kernel(
    const float* __restrict__ x,
    const float* __restrict__ wq, const float* __restrict__ wk,
    const float* __restrict__ wv, const float* __restrict__ wo,
    u16* __restrict__ xb,
    u16* __restrict__ wqb, u16* __restrict__ wkb,
    u16* __restrict__ wvb, u16* __restrict__ wob)
{
    int z = blockIdx.z;
    const float* s = (z < 4) ? x  : (z == 4 ? wq  : z == 5 ? wk  : z == 6 ? wv  : wo);
    u16*         d = (z < 4) ? xb : (z == 4 ? wqb : z == 5 ? wkb : z == 6 ? wvb : wob);
    size_t off = (z < 4) ? ((size_t)z << 20) : 0;
    size_t i = off + (size_t)blockIdx.x * 2048 + (size_t)threadIdx.x * 8;
    float4 a = *(const float4*)(s + i);
    float4 b = *(const float4*)(s + i + 4);
    s16x8 v;
    v[0] = (short)f2bf(a.x); v[1] = (short)f2bf(a.y);
    v[2] = (short)f2bf(a.z); v[3] = (short)f2bf(a.w);
    v[4] = (short)f2bf(b.x); v[5] = (short)f2bf(b.y);
    v[6] = (short)f2bf(b.z); v[7] = (short)f2bf(b.w);
    *(s16x8*)(d + i) = v;
}

// ---------------------------------------------------------------------------
// QKV GEMM: C = A @ W^T. 128x128 tile, BK=64, 256 threads, 2 blocks/CU.
// (64x128 retile tested r12: -10 us — W-panel staging doubles; keep 128sq.)
// XOR chunk swizzle: chunk c of row r stored at c ^ (r&7).
// z<2 : bf16 scatter -> [B,H,N,DH] (Q,K) + fused hyperbolic tables
// z==2: bf16 transposed scatter -> [B,H,DH,N]  (V -> Vt, fused)
// ---------------------------------------------------------------------------
__global__ __launch_bounds__(256, 2) void gemm_bt(
    const u16* __restrict__ A,
    const u16* __restrict__ W0, const u16* __restrict__ W1, const u16* __restrict__ W2,
    void* __restrict__ C0, void* __restrict__ C1, void* __restrict__ C2,
    float2* __restrict__ qtab, float2* __restrict__ ktab)
{
    __shared__ __align__(16) char smem[32768];
    char* ldsA = smem;            // 16KB: 128 rows x 8 chunks x 16B
    char* ldsW = smem + 16384;

    const u16* W = (blockIdx.z == 0) ? W0 : (blockIdx.z == 1 ? W1 : W2);
    void*      C = (blockIdx.z == 0) ? C0 : (blockIdx.z == 1 ? C1 : C2);

    const int tid  = threadIdx.x;
    const int lane = tid & 63;
    const int w    = tid >> 6;
    const int quad = lane >> 4;
    const int l15  = lane & 15;
    const int m0   = blockIdx.y * 128;
    const int n0   = blockIdx.x * 128;
    const int wr   = (w >> 1) * 64;
    const int wc   = (w & 1) * 64;

    f32x4 acc[4][4];
    const f32x4 fz = {0.f, 0.f, 0.f, 0.f};
    #pragma unroll
    for (int i = 0; i < 4; i++)
        #pragma unroll
        for (int j = 0; j < 4; j++) acc[i][j] = fz;

    for (int k0 = 0; k0 < DMODEL; k0 += 64) {
        __syncthreads();
        #pragma unroll
        for (int i = 0; i < 4; i++) {
            int linear = tid + i * 256;          // 0..1023
            int row = linear >> 3;
            int sc  = linear & 7;
            int gc  = sc ^ (row & 7);
            load16_to_lds(A + (size_t)(m0 + row) * DMODEL + k0 + gc * 8, ldsA + linear * 16);
            load16_to_lds(W + (size_t)(n0 + row) * DMODEL + k0 + gc * 8, ldsW + linear * 16);
        }
        __syncthreads();
        #pragma unroll
        for (int ks = 0; ks < 2; ks++) {
            s16x8 af[4], bf[4];
            #pragma unroll
            for (int mi = 0; mi < 4; mi++) {
                int row = wr + mi * 16 + l15;
                int ch  = (ks * 4 + quad) ^ (row & 7);
                af[mi] = *(const s16x8*)(ldsA + row * 128 + ch * 16);
            }
            #pragma unroll
            for (int ni = 0; ni < 4; ni++) {
                int row = wc + ni * 16 + l15;
                int ch  = (ks * 4 + quad) ^ (row & 7);
                bf[ni] = *(const s16x8*)(ldsW + row * 128 + ch * 16);
            }
            #pragma unroll
            for (int mi = 0; mi < 4; mi++)
                #pragma unroll
                for (int ni = 0; ni < 4; ni++)
                    acc[mi][ni] = __builtin_amdgcn_mfma_f32_16x16x32_bf16(
                        af[mi], bf[ni], acc[mi][ni], 0, 0, 0);
        }
    }

    if (blockIdx.z < 2) {
        // Q / K: scatter + fused factor tables.
        float2* tab = (blockIdx.z == 0) ? qtab : ktab;
        int h = (n0 + wc) >> 6;      // wave's 64-col span = one head
        #pragma unroll
        for (int mi = 0; mi < 4; mi++)
            #pragma unroll
            for (int r = 0; r < 4; r++) {
                int m = m0 + wr + mi * 16 + quad * 4 + r;
                int b = m >> 11, n = m & (NSEQ - 1);
                float ss = 0.f;
                #pragma unroll
                for (int ni = 0; ni < 4; ni++) {
                    int o = n0 + wc + ni * 16 + l15;
                    int d = o & 63;
                    float v = acc[mi][ni][r];
                    ss = fmaf(v, v, ss);
                    ((u16*)C)[(((size_t)(b * NH + h)) * NSEQ + n) * DH + d] = f2bf(v);
                }
                // butterfly over the 16-lane group
                ss += __shfl_xor(ss, 1);
                ss += __shfl_xor(ss, 2);
                ss += __shfl_xor(ss, 4);
                ss += __shfl_xor(ss, 8);
                if (l15 == 0) {
                    float rr = 1.0f / (1.0f - ss);
                    tab[(size_t)(b * NH + h) * NSEQ + n] =
                        make_float2((1.0f + ss) * rr, 2.0f * rr);
                }
            }
    } else {
        // V transposed: r=0..3 are consecutive n -> packed 8B stores
        #pragma unroll
        for (int mi = 0; mi < 4; mi++) {
            int mrow = m0 + wr + mi * 16 + quad * 4;
            int b = mrow >> 11, n = mrow & (NSEQ - 1);
            #pragma unroll
            for (int ni = 0; ni < 4; ni++) {
                int o = n0 + wc + ni * 16 + l15;
                int h = o >> 6, d = o & 63;
                uint2 st;
                st.x = pk2(acc[mi][ni][0], acc[mi][ni][1]);
                st.y = pk2(acc[mi][ni][2], acc[mi][ni][3]);
                *(uint2*)((u16*)C + (((size_t)(b * NH + h)) * DH + d) * NSEQ + n) = st;
            }
        }
    }
}

// ---------------------------------------------------------------------------
// Output-projection GEMM: C(fp32) = A @ W^T with 64(M)x128(N) tiles.
// 4096/64 x 1024/128 = 512 blocks -> exactly 2 blocks/CU (vs 256 blocks =
// 1/CU = 4 waves/CU for the 128-row tile) -- occupancy-motivated variant.
// 256 threads; wave = 32 rows x 64 cols (acc 2x4).  LDS 24KB.
// ---------------------------------------------------------------------------
__global__ __launch_bounds__(256, 2) void gemm_m64(
    const u16* __restrict__ A, const u16* __restrict__ W, float* __restrict__ C)
{
    __shared__ __align__(16) char smem[24576];
    char* ldsA = smem;            // 8KB: 64 rows x 8 chunks x 16B
    char* ldsW = smem + 8192;     // 16KB: 128 rows x 8 chunks

    const int tid  = threadIdx.x;
    const int lane = tid & 63;
    const int w    = tid >> 6;
    const int quad = lane >> 4;
    const int l15  = lane & 15;
    const int m0   = blockIdx.y * 64;
    const int n0   = blockIdx.x * 128;
    const int wr   = (w >> 1) * 32;
    const int wc   = (w & 1) * 64;

    f32x4 acc[2][4];
    const f32x4 fz = {0.f, 0.f, 0.f, 0.f};
    #pragma unroll
    for (int i = 0; i < 2; i++)
        #pragma unroll
        for (int j = 0; j < 4; j++) acc[i][j] = fz;

    for (int k0 = 0; k0 < DMODEL; k0 += 64) {
        __syncthreads();
        #pragma unroll
        for (int i = 0; i < 2; i++) {           // A: 512 chunks
            int linear = tid + i * 256;
            int row = linear >> 3, sc = linear & 7, gc = sc ^ (row & 7);
            load16_to_lds(A + (size_t)(m0 + row) * DMODEL + k0 + gc * 8,
                          ldsA + linear * 16);
        }
        #pragma unroll
        for (int i = 0; i < 4; i++) {           // W: 1024 chunks
            int linear = tid + i * 256;
            int row = linear >> 3, sc = linear & 7, gc = sc ^ (row & 7);
            load16_to_lds(W + (size_t)(n0 + row) * DMODEL + k0 + gc * 8,
                          ldsW + linear * 16);
        }
        __syncthreads();
        #pragma unroll
        for (int ks = 0; ks < 2; ks++) {
            s16x8 af[2], bf[4];
            #pragma unroll
            for (int mi = 0; mi < 2; mi++) {
                int row = wr + mi * 16 + l15;
                int ch  = (ks * 4 + quad) ^ (row & 7);
                af[mi] = *(const s16x8*)(ldsA + row * 128 + ch * 16);
            }
            #pragma unroll
            for (int ni = 0; ni < 4; ni++) {
                int row = wc + ni * 16 + l15;
                int ch  = (ks * 4 + quad) ^ (row & 7);
                bf[ni] = *(const s16x8*)(ldsW + row * 128 + ch * 16);
            }
            #pragma unroll
            for (int mi = 0; mi < 2; mi++)
                #pragma unroll
                for (int ni = 0; ni < 4; ni++)
                    acc[mi][ni] = __builtin_amdgcn_mfma_f32_16x16x32_bf16(
                        af[mi], bf[ni], acc[mi][ni], 0, 0, 0);
        }
    }

    #pragma unroll
    for (int mi = 0; mi < 2; mi++)
        #pragma unroll
        for (int r = 0; r < 4; r++) {
            int m = m0 + wr + mi * 16 + quad * 4 + r;
            #pragma unroll
            for (int ni = 0; ni < 4; ni++) {
                int o = n0 + wc + ni * 16 + l15;
                C[(size_t)m * DMODEL + o] = acc[mi][ni][r];
            }
        }
}

// ---------------------------------------------------------------------------
// Attention, transposed-score form, 32 q per wave, IN-BLOCK kv-split.
// grid (NSEQ/128, BH), 512 threads (8 waves): waves 0-3 = j in [0,1024),
// waves 4-7 = j in [1024,2048), same 128-q tile.  Each group stages its own
// K/Vt tiles in its 32KB half of LDS.  Epilogue: group 1 drops fp32
// oacc/lsum into LDS (stride-68 pad), group 0 adds, normalizes, writes Attw.
// Scalar transform (pk-f32 variants spill -- do not revisit).
// PLATEAU: occupancy reg-capped (16 waves x ~104 = 1664/2048); LDS 64KB.
// ---------------------------------------------------------------------------
__global__ __launch_bounds__(512, 4) void attn_kernel(
    const u16* __restrict__ Q,      // [BH][NSEQ][DH]
    const u16* __restrict__ K,      // [BH][NSEQ][DH]
    const u16* __restrict__ Vt,     // [BH][DH][NSEQ]
    const float2* __restrict__ qtab,
    const float2* __restrict__ ktab,
    u16* __restrict__ Attw)         // [B][NSEQ][DMODEL] bf16
{
    __shared__ __align__(16) char smem[65536];

    const int tid  = threadIdx.x;
    const int lane = tid & 63;
    const int w    = tid >> 6;       // 0..7
    const int g    = w >> 2;         // j-half group
    const int wq_  = w & 3;
    const int quad = lane >> 4;
    const int l15  = lane & 15;
    const int bh   = blockIdx.y;
    const int i0   = blockIdx.x * 128;
    const int qbase = i0 + wq_ * 32;
    const int gt   = tid & 255;      // tid within group

    char* ldsK = smem + g * 16384;
    char* ldsV = smem + 32768 + g * 16384;

    // Q fragments (B-operand layout), pre-scaled by Rr
    s16x8 qf[2][2];                 // [qt][ks]
    float Pr[2];
    #pragma unroll
    for (int qt = 0; qt < 2; qt++) {
        int qrow = qbase + qt * 16 + l15;
        float2 qt2 = qtab[(size_t)bh * NSEQ + qrow];
        Pr[qt] = qt2.x;
        float Rr = qt2.y;
        #pragma unroll
        for (int ks = 0; ks < 2; ks++) {
            s16x8 raw = *(const s16x8*)(Q + ((size_t)bh * NSEQ + qrow) * DH
                                        + ks * 32 + quad * 8);
            s16x8 sc;
            #pragma unroll
            for (int e = 0; e < 8; e++)
                sc[e] = (short)f2bf(bf2f((u16)raw[e]) * Rr);
            qf[qt][ks] = sc;
        }
    }

    // bpermute source-lane byte indices
    const int idx0 = ((quad & 1) * 32 + l15) * 4;
    const int idx2 = idx0 + 64;
    const bool selhi = quad >= 2;

    const f32x4 fz = {0.f, 0.f, 0.f, 0.f};
    f32x4 oacc[2][4];               // [qt][d-tile], O^T C-layout (col=q, row=d)
    f32x4 lsum[2];
    #pragma unroll
    for (int qt = 0; qt < 2; qt++) {
        lsum[qt] = fz;
        #pragma unroll
        for (int ni = 0; ni < 4; ni++) oacc[qt][ni] = fz;
    }

    s16x8 ones;
    #pragma unroll
    for (int j = 0; j < 8; j++) ones[j] = (short)0x3F80;  // bf16 1.0

    const float2* ktb = ktab + (size_t)bh * NSEQ;

    for (int jj = 0; jj < NSEQ / 2; jj += 128) {
        int j0 = g * (NSEQ / 2) + jj;
        __syncthreads();
        #pragma unroll
        for (int i = 0; i < 4; i++) {
            int linear = gt + i * 256;    // 0..1023 within group
            {   // K tile: 128 rows x 8 chunks, swz8
                int row = linear >> 3, sc = linear & 7, gc = sc ^ (row & 7);
                load16_to_lds(K + ((size_t)bh * NSEQ + j0 + row) * DH + gc * 8,
                              ldsK + linear * 16);
            }
            {   // Vt tile: 64 rows x 16 chunks, swz16
                int d = linear >> 4, sc = linear & 15, gc = sc ^ (d & 15);
                load16_to_lds(Vt + ((size_t)bh * DH + d) * NSEQ + j0 + gc * 8,
                              ldsV + linear * 16);
            }
        }
        __syncthreads();

        #pragma unroll
        for (int cb = 0; cb < 4; cb++) {          // 32 j per chunk
            // S' = K Q'^T: two 16-j tiles x two q-tiles (kf shared across qt)
            f32x4 s2[2][2];                       // [qt][t]
            #pragma unroll
            for (int qt = 0; qt < 2; qt++)
                #pragma unroll
                for (int t = 0; t < 2; t++) s2[qt][t] = fz;
            #pragma unroll
            for (int t = 0; t < 2; t++) {
                int row = (cb * 2 + t) * 16 + l15;
                #pragma unroll
                for (int ks = 0; ks < 2; ks++) {
                    s16x8 kf = *(const s16x8*)(ldsK + row * 128
                                 + (((ks * 4 + quad) ^ (row & 7)) * 16));
                    #pragma unroll
                    for (int qt = 0; qt < 2; qt++)
                        s2[qt][t] = __builtin_amdgcn_mfma_f32_16x16x32_bf16(
                            kf, qf[qt][ks], s2[qt][t], 0, 0, 0);
                }
            }
            // transform + pack: z = Pr*Pc - s2*Rc (scalar form)
            uint32_t d0[2][2], d1[2][2];          // [qt][t]
            #pragma unroll
            for (int t = 0; t < 2; t++) {
                const f32x4* kt = (const f32x4*)(ktb + j0 + (cb * 2 + t) * 16 + quad * 4);
                f32x4 c01 = kt[0], c23 = kt[1];
                #pragma unroll
                for (int qt = 0; qt < 2; qt++) {
                    float z0 = fmaf(-s2[qt][t][0], c01.y, Pr[qt] * c01.x);
                    float z1 = fmaf(-s2[qt][t][1], c01.w, Pr[qt] * c01.z);
                    float z2 = fmaf(-s2[qt][t][2], c23.y, Pr[qt] * c23.x);
                    float z3 = fmaf(-s2[qt][t][3], c23.w, Pr[qt] * c23.z);
                    z0 = fmaxf(z0, 1.0f); z1 = fmaxf(z1, 1.0f);
                    z2 = fmaxf(z2, 1.0f); z3 = fmaxf(z3, 1.0f);
                    float p0 = z0 - __builtin_amdgcn_sqrtf(fmaf(z0, z0, -1.0f));
                    float p1 = z1 - __builtin_amdgcn_sqrtf(fmaf(z1, z1, -1.0f));
                    float p2 = z2 - __builtin_amdgcn_sqrtf(fmaf(z2, z2, -1.0f));
                    float p3 = z3 - __builtin_amdgcn_sqrtf(fmaf(z3, z3, -1.0f));
                    d0[qt][t] = pk2(p0, p1);
                    d1[qt][t] = pk2(p2, p3);
                }
            }
            // build P' B-fragments via cross-lane pulls
            s16x8 pf[2];
            #pragma unroll
            for (int qt = 0; qt < 2; qt++) {
                int a0 = __builtin_amdgcn_ds_bpermute(idx0, (int)d0[qt][0]);
                int b0 = __builtin_amdgcn_ds_bpermute(idx0, (int)d0[qt][1]);
                int a1 = __builtin_amdgcn_ds_bpermute(idx0, (int)d1[qt][0]);
                int b1 = __builtin_amdgcn_ds_bpermute(idx0, (int)d1[qt][1]);
                int a2 = __builtin_amdgcn_ds_bpermute(idx2, (int)d0[qt][0]);
                int b2 = __builtin_amdgcn_ds_bpermute(idx2, (int)d0[qt][1]);
                int a3 = __builtin_amdgcn_ds_bpermute(idx2, (int)d1[qt][0]);
                int b3 = __builtin_amdgcn_ds_bpermute(idx2, (int)d1[qt][1]);
                union { int i[4]; s16x8 v; } pu;
                pu.i[0] = selhi ? b0 : a0;
                pu.i[1] = selhi ? b1 : a1;
                pu.i[2] = selhi ? b2 : a2;
                pu.i[3] = selhi ? b3 : a3;
                pf[qt] = pu.v;
            }

            // O^T += Vt-tile * P' (vf shared across qt) ; lsum += ones * P'
            #pragma unroll
            for (int ni = 0; ni < 4; ni++) {
                int d = ni * 16 + l15;
                s16x8 vf = *(const s16x8*)(ldsV + d * 256
                             + (((cb * 4 + quad) ^ (d & 15)) * 16));
                #pragma unroll
                for (int qt = 0; qt < 2; qt++)
                    oacc[qt][ni] = __builtin_amdgcn_mfma_f32_16x16x32_bf16(
                        vf, pf[qt], oacc[qt][ni], 0, 0, 0);
            }
            #pragma unroll
            for (int qt = 0; qt < 2; qt++)
                lsum[qt] = __builtin_amdgcn_mfma_f32_16x16x32_bf16(
                    ones, pf[qt], lsum[qt], 0, 0, 0);
        }
    }

    // ---- in-block combine: group 1 -> LDS, group 0 adds + stores ----
    __syncthreads();
    float* oxfer = (float*)smem;                 // [128 q][68] fp32 (pad 68)
    float* lxfer = (float*)(smem + 34816);       // [128] fp32
    if (g == 1) {
        #pragma unroll
        for (int qt = 0; qt < 2; qt++) {
            int ql = wq_ * 32 + qt * 16 + l15;
            #pragma unroll
            for (int ni = 0; ni < 4; ni++)
                *(f32x4*)(oxfer + ql * 68 + ni * 16 + quad * 4) = oacc[qt][ni];
            if (quad == 0) lxfer[ql] = lsum[qt][0];
        }
    }
    __syncthreads();
    if (g == 0) {
        const int b = bh >> 4, h = bh & 15;
        #pragma unroll
        for (int qt = 0; qt < 2; qt++) {
            int ql = wq_ * 32 + qt * 16 + l15;
            float rls = 1.0f / (lsum[qt][0] + lxfer[ql]);
            size_t obase = ((size_t)b * NSEQ + qbase + qt * 16 + l15) * DMODEL
                           + h * DH + quad * 4;
            #pragma unroll
            for (int ni = 0; ni < 4; ni++) {
                f32x4 add = *(const f32x4*)(oxfer + ql * 68 + ni * 16 + quad * 4);
                f32x4 o = oacc[qt][ni] + add;
                uint2 st;
                st.x = pk2(o[0] * rls, o[1] * rls);
                st.y = pk2(o[2] * rls, o[3] * rls);
                *(uint2*)(Attw + obase + ni * 16) = st;
            }
        }
    }
}

// ---------------------------------------------------------------------------
extern "C" void kernel_launch(void* const* d_in, const int* in_sizes, int n_in,
                              void* d_out, int out_size, void* d_ws, size_t ws_size,
                              hipStream_t stream)
{
    const float* x  = (const float*)d_in[0];
    const float* wq = (const float*)d_in[1];
    const float* wk = (const float*)d_in[2];
    const float* wv = (const float*)d_in[3];
    const float* wo = (const float*)d_in[4];
    float* out = (float*)d_out;

    const size_t QSZ = (size_t)BH * NSEQ * DH;   // 4,194,304 elements
    const size_t WSZ = (size_t)DMODEL * DMODEL;  // 1,048,576 elements
    u16* xb   = (u16*)d_ws;           // 4M elem; reused as Attw after attn
    u16* wqb  = xb  + QSZ;
    u16* wkb  = wqb + WSZ;
    u16* wvb  = wkb + WSZ;
    u16* wob  = wvb + WSZ;
    u16* Qw   = wob + WSZ;
    u16* Kw   = Qw + QSZ;
    u16* Vtw  = Kw + QSZ;             // V written pre-transposed by gemm
    float2* qtab = (float2*)(Vtw + QSZ);
    float2* ktab = qtab + (size_t)BH * NSEQ;
    u16*    Attw = xb;                // overlay: x bf16 dead after QKV

    // 0. fp32 -> bf16 conversions
    cvt_kernel<<<dim3(512, 1, 8), 256, 0, stream>>>(x, wq, wk, wv, wo,
                                                    xb, wqb, wkb, wvb, wob);
    // 1. Q/K/V projections; V pre-transposed; Q/K factor tables fused
    gemm_bt<<<dim3(8, 32, 3), 256, 0, stream>>>(xb, wqb, wkb, wvb, Qw, Kw, Vtw,
                                                qtab, ktab);
    // 2. attention (32 q/wave, in-block kv-split, writes Attw directly)
    attn_kernel<<<dim3(NSEQ / 128, BH), 512, 0, stream>>>(Qw, Kw, Vtw, qtab, ktab,
                                                          Attw);
    // 3. output projection -> d_out (fp32), 64-row tiles for 2 blocks/CU
    gemm_m64<<<dim3(8, 64), 256, 0, stream>>>(Attw, wob, out);
}